// Round 1
// baseline (331.408 us; speedup 1.0000x reference)
//
#include <hip/hip_runtime.h>

#define C_DIM 256
#define G_DIM 16
#define P_DIM 9
#define OMD 432
#define H_DIM 56
#define W_DIM 56
#define HW 3136
#define N_B 8
#define M_ROWS 25088   // N_B * HW

// ---------------------------------------------------------------------------
// Tiled fp32 GEMM:  Y[r, j] = sum_c A[r,c] * W[j,c] + bias[j]
//   A_NCHW:  A[r,c] = x[(n*256 + c)*3136 + p]   (r = n*3136 + p)
//   else:    A[r,c] = A[r*256 + c]
//   OUT_NCHW: Y -> d_out[(n*256 + j)*3136 + p]
//   else:     Y -> Y[r*Nout + j]
// Tile: 64x64 output, BK=16, 256 threads, 4x4 per thread.
// ---------------------------------------------------------------------------
template <bool A_NCHW, bool OUT_NCHW>
__global__ __launch_bounds__(256) void gemm_k(const float* __restrict__ A,
                                              const float* __restrict__ W,
                                              const float* __restrict__ bias,
                                              float* __restrict__ Y, int Nout) {
  __shared__ float As[16][68];
  __shared__ float Bs[16][68];
  const int tid = threadIdx.x;
  const int tx = tid & 15;        // output col group
  const int ty = tid >> 4;        // output row group
  const int rblk = blockIdx.y * 64;
  const int jblk = blockIdx.x * 64;

  // A-load mapping: linear li = tid + 256*i -> m = tid&63 (fixed), k = (tid>>6)+4*i
  const int lm = tid & 63;
  const int lkb = tid >> 6;
  const int r_l = rblk + lm;
  size_t abase;
  if (A_NCHW) {
    const int n = r_l / HW;
    const int p = r_l % HW;
    abase = (size_t)n * (C_DIM * HW) + p;
  } else {
    abase = (size_t)r_l * C_DIM;
  }

  // B-load mapping: li = tid + 256*i -> kk = tid&15 (fixed), jj = (tid>>4)+16*i
  const int bkk = tid & 15;
  const int bjb = tid >> 4;

  float acc[4][4];
#pragma unroll
  for (int i = 0; i < 4; ++i)
#pragma unroll
    for (int j = 0; j < 4; ++j) acc[i][j] = 0.f;

  for (int k0 = 0; k0 < C_DIM; k0 += 16) {
#pragma unroll
    for (int i = 0; i < 4; ++i) {
      const int k = lkb + 4 * i;
      As[k][lm] = A_NCHW ? A[abase + (size_t)(k0 + k) * HW] : A[abase + k0 + k];
    }
#pragma unroll
    for (int i = 0; i < 4; ++i) {
      const int jj = bjb + 16 * i;
      const int jg = jblk + jj;
      Bs[bkk][jj] = (jg < Nout) ? W[(size_t)jg * C_DIM + k0 + bkk] : 0.f;
    }
    __syncthreads();
#pragma unroll
    for (int kk = 0; kk < 16; ++kk) {
      float a[4], b[4];
#pragma unroll
      for (int i = 0; i < 4; ++i) a[i] = As[kk][ty * 4 + i];
#pragma unroll
      for (int j = 0; j < 4; ++j) b[j] = Bs[kk][tx * 4 + j];
#pragma unroll
      for (int i = 0; i < 4; ++i)
#pragma unroll
        for (int j = 0; j < 4; ++j) acc[i][j] = fmaf(a[i], b[j], acc[i][j]);
    }
    __syncthreads();
  }

#pragma unroll
  for (int i = 0; i < 4; ++i) {
    const int r = rblk + ty * 4 + i;
    int n, p;
    if (OUT_NCHW) { n = r / HW; p = r % HW; }
#pragma unroll
    for (int j = 0; j < 4; ++j) {
      const int col = jblk + tx * 4 + j;
      if (col < Nout) {
        const float v = acc[i][j] + bias[col];
        if (OUT_NCHW)
          Y[(size_t)(n * C_DIM + col) * HW + p] = v;
        else
          Y[(size_t)r * Nout + col] = v;
      }
    }
  }
}

// ---------------------------------------------------------------------------
// DCNv4 core: one block per output row r (=n,h,w); 256 threads = 16 groups x 16 ch.
// ---------------------------------------------------------------------------
__global__ __launch_bounds__(256) void dcn_core(const float* __restrict__ val,
                                                const float* __restrict__ om,
                                                float* __restrict__ core) {
  const int r = blockIdx.x;
  __shared__ float oms[OMD];
  const int tid = threadIdx.x;
  oms[tid] = om[(size_t)r * OMD + tid];
  if (tid < OMD - 256) oms[256 + tid] = om[(size_t)r * OMD + 256 + tid];
  __syncthreads();

  const int g = tid >> 4;
  const int n = r / HW;
  const int p = r % HW;
  const int h = p / W_DIM;
  const int w = p % W_DIM;
  const float* vbase = val + (size_t)n * HW * C_DIM + tid;  // tid == g*16+cc
  const float* og = &oms[g * 27];

  float acc = 0.f;
#pragma unroll
  for (int pp = 0; pp < P_DIM; ++pp) {
    const int ii = pp / 3;
    const int jj = pp - 3 * ii;
    const float offx = og[2 * pp];
    const float offy = og[2 * pp + 1];
    const float m = og[18 + pp];
    const float lh_f = (float)(h - 1 + ii) + offy;
    const float lw_f = (float)(w - 1 + jj) + offx;
    const float h0f = floorf(lh_f);
    const float w0f = floorf(lw_f);
    const float lh = lh_f - h0f;
    const float lw = lw_f - w0f;
    const int h0 = (int)h0f;
    const int w0 = (int)w0f;
    const bool hv0 = (h0 >= 0) && (h0 < H_DIM);
    const bool hv1 = (h0 + 1 >= 0) && (h0 + 1 < H_DIM);
    const bool wv0 = (w0 >= 0) && (w0 < W_DIM);
    const bool wv1 = (w0 + 1 >= 0) && (w0 + 1 < W_DIM);
    float v00 = 0.f, v01 = 0.f, v10 = 0.f, v11 = 0.f;
    if (hv0) {
      const float* rowp = vbase + (size_t)(h0 * W_DIM) * C_DIM;
      if (wv0) v00 = rowp[(size_t)w0 * C_DIM];
      if (wv1) v01 = rowp[(size_t)(w0 + 1) * C_DIM];
    }
    if (hv1) {
      const float* rowp = vbase + (size_t)((h0 + 1) * W_DIM) * C_DIM;
      if (wv0) v10 = rowp[(size_t)w0 * C_DIM];
      if (wv1) v11 = rowp[(size_t)(w0 + 1) * C_DIM];
    }
    const float bil = (1.f - lh) * ((1.f - lw) * v00 + lw * v01) +
                      lh * ((1.f - lw) * v10 + lw * v11);
    acc = fmaf(m, bil, acc);
  }
  core[(size_t)r * C_DIM + tid] = acc;
}

extern "C" void kernel_launch(void* const* d_in, const int* in_sizes, int n_in,
                              void* d_out, int out_size, void* d_ws, size_t ws_size,
                              hipStream_t stream) {
  const float* x       = (const float*)d_in[0];
  const float* value_w = (const float*)d_in[1];
  const float* value_b = (const float*)d_in[2];
  const float* om_w    = (const float*)d_in[3];
  const float* om_b    = (const float*)d_in[4];
  const float* out_w   = (const float*)d_in[5];
  const float* out_b   = (const float*)d_in[6];
  float* out = (float*)d_out;

  // workspace layout (fp32): val [25088*256] | om [25088*432] | core [25088*256]
  float* val  = (float*)d_ws;
  float* om   = val + (size_t)M_ROWS * C_DIM;
  float* core = om + (size_t)M_ROWS * OMD;

  dim3 blk(256);
  // val = xp @ value_w.T + value_b
  gemm_k<true, false><<<dim3(4, 392), blk, 0, stream>>>(x, value_w, value_b, val, C_DIM);
  // om = xp @ om_w.T + om_b
  gemm_k<true, false><<<dim3(7, 392), blk, 0, stream>>>(x, om_w, om_b, om, OMD);
  // deformable sampling
  dcn_core<<<dim3(M_ROWS), blk, 0, stream>>>(val, om, core);
  // out = core @ out_w.T + out_b, written NCHW
  gemm_k<false, true><<<dim3(4, 392), blk, 0, stream>>>(core, out_w, out_b, out, C_DIM);
}

// Round 2
// 134.733 us; speedup vs baseline: 2.4597x; 2.4597x over previous
//
#include <hip/hip_runtime.h>
#include <hip/hip_bf16.h>

#define C_DIM 256
#define G_DIM 16
#define P_DIM 9
#define OMD 432
#define OMD_PAD 512
#define H_DIM 56
#define W_DIM 56
#define HW 3136
#define N_B 8
#define M_ROWS 25088   // N_B * HW

typedef __bf16 bf16x8 __attribute__((ext_vector_type(8)));
typedef float f32x4 __attribute__((ext_vector_type(4)));

__device__ inline unsigned short f2bf(float f) {
  unsigned u = __float_as_uint(f);
  unsigned r = u + 0x7fffu + ((u >> 16) & 1u);   // RNE
  return (unsigned short)(r >> 16);
}

__device__ inline void gload_lds16(const void* g, void* l) {
  __builtin_amdgcn_global_load_lds(
      (const __attribute__((address_space(1))) void*)g,
      (__attribute__((address_space(3))) void*)l, 16, 0, 0);
}

// ---------------------------------------------------------------------------
// Weight conversion: value_w, out_w -> bf16; om_w -> bf16 zero-padded to 512 rows.
// ---------------------------------------------------------------------------
__global__ __launch_bounds__(256) void convert_w(const float* __restrict__ vw,
                                                 const float* __restrict__ owt,
                                                 const float* __restrict__ omw,
                                                 unsigned short* __restrict__ wv,
                                                 unsigned short* __restrict__ ow,
                                                 unsigned short* __restrict__ wom) {
  int i = blockIdx.x * 256 + threadIdx.x;
  if (i < 65536) {
    wv[i] = f2bf(vw[i]);
  } else if (i < 131072) {
    ow[i - 65536] = f2bf(owt[i - 65536]);
  } else {
    int j = i - 131072;           // 0 .. 512*256-1
    int row = j >> 8;
    wom[j] = (row < OMD) ? f2bf(omw[j]) : (unsigned short)0;
  }
}

// ---------------------------------------------------------------------------
// x (N,C,H,W) fp32 -> xp (N*HW, C) bf16 via 32x32 LDS tile transpose.
// grid (98, 8, 8): pblk = bx*32, cblk = by*32, n = bz
// ---------------------------------------------------------------------------
__global__ __launch_bounds__(256) void convert_x(const float* __restrict__ x,
                                                 unsigned short* __restrict__ xp) {
  __shared__ float t[32][33];
  const int tid = threadIdx.x;
  const int pblk = blockIdx.x * 32, cblk = blockIdx.y * 32, n = blockIdx.z;
  const int lp = tid & 31;
  const int c0 = tid >> 5;      // 0..7
#pragma unroll
  for (int i = 0; i < 4; ++i) {
    const int cl = c0 + i * 8;
    t[cl][lp] = x[(size_t)(n * C_DIM + cblk + cl) * HW + pblk + lp];
  }
  __syncthreads();
  const int co = tid & 31;
  const int r0 = tid >> 5;
#pragma unroll
  for (int i = 0; i < 4; ++i) {
    const int rl = r0 + i * 8;
    xp[(size_t)(n * HW + pblk + rl) * C_DIM + cblk + co] = f2bf(t[co][rl]);
  }
}

// ---------------------------------------------------------------------------
// bf16 MFMA GEMM: Y[r,j] = sum_k A[r,k]*B[j,k] + bias[j]
// A: [M][256] bf16 row-major, B: [Npad][256] bf16 row-major.
// 128x128 tile, BK=32, 256 threads (2x2 waves, each 64x64).
// OUTMODE 0: bf16 row-major stride 256
// OUTMODE 1: fp32 row-major stride OMD, predicated col < OMD
// OUTMODE 2: fp32 NCHW (n*256+col)*HW + p
// ---------------------------------------------------------------------------
template <int OUTMODE>
__global__ __launch_bounds__(256) void gemm_mfma(const unsigned short* __restrict__ A,
                                                 const unsigned short* __restrict__ B,
                                                 const float* __restrict__ bias,
                                                 void* __restrict__ Y) {
  __shared__ unsigned short Asl[128 * 32];
  __shared__ unsigned short Bsl[128 * 32];
  const int tid = threadIdx.x;
  const int wave = tid >> 6;
  const int lane = tid & 63;
  const int rblk = blockIdx.y * 128;
  const int jblk = blockIdx.x * 128;
  const int wm = wave >> 1, wn = wave & 1;
  const int lrow = lane & 15;     // fragment row (A) / col (B) / output col
  const int lk8 = lane >> 4;      // k-chunk (input) / row-quad (output)

  f32x4 acc[4][4];
#pragma unroll
  for (int i = 0; i < 4; ++i)
#pragma unroll
    for (int j = 0; j < 4; ++j) acc[i][j] = f32x4{0.f, 0.f, 0.f, 0.f};

  // staging map: li = tid + 256*i -> row = li>>2, kseg = li&3 ; LDS linear = li*16B
  const int srow0 = tid >> 2;
  const int skseg = tid & 3;

  for (int k0 = 0; k0 < C_DIM; k0 += 32) {
#pragma unroll
    for (int i = 0; i < 2; ++i) {
      const int row = srow0 + i * 64;
      const size_t goff = (size_t)row * C_DIM + k0 + skseg * 8;
      char* lA = (char*)Asl + (wave * 64 + i * 256) * 16;
      char* lB = (char*)Bsl + (wave * 64 + i * 256) * 16;
      gload_lds16(A + (size_t)(rblk + row) * C_DIM + k0 + skseg * 8, lA);
      gload_lds16(B + (size_t)(jblk + row) * C_DIM + k0 + skseg * 8, lB);
      (void)goff;
    }
    __syncthreads();
    bf16x8 a[4], b[4];
#pragma unroll
    for (int mi = 0; mi < 4; ++mi)
      a[mi] = *(const bf16x8*)&Asl[(wm * 64 + mi * 16 + lrow) * 32 + lk8 * 8];
#pragma unroll
    for (int nj = 0; nj < 4; ++nj)
      b[nj] = *(const bf16x8*)&Bsl[(wn * 64 + nj * 16 + lrow) * 32 + lk8 * 8];
#pragma unroll
    for (int mi = 0; mi < 4; ++mi)
#pragma unroll
      for (int nj = 0; nj < 4; ++nj)
        acc[mi][nj] = __builtin_amdgcn_mfma_f32_16x16x32_bf16(a[mi], b[nj], acc[mi][nj], 0, 0, 0);
    __syncthreads();
  }

#pragma unroll
  for (int nj = 0; nj < 4; ++nj) {
    const int col = jblk + wn * 64 + nj * 16 + lrow;
    float bs;
    if (OUTMODE == 1) bs = (col < OMD) ? bias[col] : 0.f;
    else bs = bias[col];
#pragma unroll
    for (int mi = 0; mi < 4; ++mi) {
#pragma unroll
      for (int rg = 0; rg < 4; ++rg) {
        const int r = rblk + wm * 64 + mi * 16 + lk8 * 4 + rg;
        const float v = acc[mi][nj][rg] + bs;
        if (OUTMODE == 0) {
          ((unsigned short*)Y)[(size_t)r * C_DIM + col] = f2bf(v);
        } else if (OUTMODE == 1) {
          if (col < OMD) ((float*)Y)[(size_t)r * OMD + col] = v;
        } else {
          const int n = r / HW;
          const int p = r - n * HW;
          ((float*)Y)[(size_t)(n * C_DIM + col) * HW + p] = v;
        }
      }
    }
  }
}

// ---------------------------------------------------------------------------
// DCNv4 core. Block = 256 threads = 2 pixels x (16 groups x 8 ch-pairs).
// val: bf16 [M][256], om: fp32 [M][432], core out: bf16 [M][256].
// ---------------------------------------------------------------------------
__global__ __launch_bounds__(256) void dcn_core(const unsigned* __restrict__ val_u,
                                                const float* __restrict__ om,
                                                unsigned* __restrict__ core_u) {
  __shared__ float oms[2 * OMD];
  const int tid = threadIdx.x;
  const int rbase = blockIdx.x * 2;
  for (int i = tid; i < 2 * OMD; i += 256) oms[i] = om[(size_t)rbase * OMD + i];
  __syncthreads();

  const int half = tid >> 7;
  const int t = tid & 127;
  const int g = t >> 3;          // group 0..15
  const int cp = t & 7;          // channel pair 0..7
  const int r = rbase + half;
  const int n = r / HW;
  const int p = r - n * HW;
  const int h = p / W_DIM;
  const int w = p - h * W_DIM;

  const float* og = &oms[half * OMD + g * 27];
  const unsigned* vb = val_u + (size_t)n * HW * 128 + g * 8 + cp;

  float acc0 = 0.f, acc1 = 0.f;
#pragma unroll
  for (int pp = 0; pp < P_DIM; ++pp) {
    const int ii = pp / 3;
    const int jj = pp - 3 * ii;
    const float offx = og[2 * pp];
    const float offy = og[2 * pp + 1];
    const float m = og[18 + pp];
    const float lh_f = (float)(h - 1 + ii) + offy;
    const float lw_f = (float)(w - 1 + jj) + offx;
    const float h0f = floorf(lh_f);
    const float w0f = floorf(lw_f);
    const float lh = lh_f - h0f;
    const float lw = lw_f - w0f;
    const int h0 = (int)h0f;
    const int w0 = (int)w0f;
    const bool hv0 = (h0 >= 0) & (h0 < H_DIM);
    const bool hv1 = (h0 + 1 >= 0) & (h0 + 1 < H_DIM);
    const bool wv0 = (w0 >= 0) & (w0 < W_DIM);
    const bool wv1 = (w0 + 1 >= 0) & (w0 + 1 < W_DIM);
    unsigned u00 = 0, u01 = 0, u10 = 0, u11 = 0;
    if (hv0) {
      const unsigned* rp = vb + (size_t)(h0 * W_DIM) * 128;
      if (wv0) u00 = rp[(size_t)w0 * 128];
      if (wv1) u01 = rp[(size_t)(w0 + 1) * 128];
    }
    if (hv1) {
      const unsigned* rp = vb + (size_t)((h0 + 1) * W_DIM) * 128;
      if (wv0) u10 = rp[(size_t)w0 * 128];
      if (wv1) u11 = rp[(size_t)(w0 + 1) * 128];
    }
    const float w00 = (1.f - lh) * (1.f - lw);
    const float w01 = (1.f - lh) * lw;
    const float w10 = lh * (1.f - lw);
    const float w11 = lh * lw;
    // low ushort = channel c, high ushort = channel c+1
    const float a00 = __uint_as_float(u00 << 16), b00 = __uint_as_float(u00 & 0xffff0000u);
    const float a01 = __uint_as_float(u01 << 16), b01 = __uint_as_float(u01 & 0xffff0000u);
    const float a10 = __uint_as_float(u10 << 16), b10 = __uint_as_float(u10 & 0xffff0000u);
    const float a11 = __uint_as_float(u11 << 16), b11 = __uint_as_float(u11 & 0xffff0000u);
    const float bil0 = w00 * a00 + w01 * a01 + w10 * a10 + w11 * a11;
    const float bil1 = w00 * b00 + w01 * b01 + w10 * b10 + w11 * b11;
    acc0 = fmaf(m, bil0, acc0);
    acc1 = fmaf(m, bil1, acc1);
  }
  core_u[(size_t)r * 128 + g * 8 + cp] =
      (unsigned)f2bf(acc0) | ((unsigned)f2bf(acc1) << 16);
}

extern "C" void kernel_launch(void* const* d_in, const int* in_sizes, int n_in,
                              void* d_out, int out_size, void* d_ws, size_t ws_size,
                              hipStream_t stream) {
  const float* x       = (const float*)d_in[0];
  const float* value_w = (const float*)d_in[1];
  const float* value_b = (const float*)d_in[2];
  const float* om_w    = (const float*)d_in[3];
  const float* om_b    = (const float*)d_in[4];
  const float* out_w   = (const float*)d_in[5];
  const float* out_b   = (const float*)d_in[6];
  float* out = (float*)d_out;

  // workspace layout
  char* wsb = (char*)d_ws;
  float* om = (float*)wsb;                                     // 25088*432*4 = 43352064 B
  unsigned short* xp   = (unsigned short*)(wsb + (size_t)M_ROWS * OMD * 4);
  unsigned short* valb = xp + (size_t)M_ROWS * C_DIM;
  unsigned short* coreb = valb + (size_t)M_ROWS * C_DIM;
  unsigned short* wv  = coreb + (size_t)M_ROWS * C_DIM;
  unsigned short* ow  = wv + C_DIM * C_DIM;
  unsigned short* wom = ow + C_DIM * C_DIM;                    // 512*256

  dim3 blk(256);
  convert_w<<<dim3((2 * C_DIM * C_DIM + OMD_PAD * C_DIM) / 256), blk, 0, stream>>>(
      value_w, out_w, om_w, wv, ow, wom);
  convert_x<<<dim3(98, 8, 8), blk, 0, stream>>>(x, xp);
  // val = xp @ value_w.T + value_b   (bf16 out)
  gemm_mfma<0><<<dim3(2, 196), blk, 0, stream>>>(xp, wv, value_b, valb);
  // om = xp @ om_w.T + om_b          (fp32 out, 432 cols)
  gemm_mfma<1><<<dim3(4, 196), blk, 0, stream>>>(xp, wom, om_b, om);
  // deformable sampling
  dcn_core<<<dim3(M_ROWS / 2), blk, 0, stream>>>((const unsigned*)valb, om, (unsigned*)coreb);
  // out = core @ out_w.T + out_b     (fp32 NCHW)
  gemm_mfma<2><<<dim3(2, 196), blk, 0, stream>>>(coreb, ow, out_b, out);
}

// Round 3
// 125.330 us; speedup vs baseline: 2.6443x; 1.0750x over previous
//
#include <hip/hip_runtime.h>
#include <hip/hip_bf16.h>

#define C_DIM 256
#define G_DIM 16
#define P_DIM 9
#define OMD 432
#define OMD_PAD 512
#define OM_GSTRIDE 28           // padded floats per group in om workspace
#define OM_RSTRIDE 448          // 16 * 28 floats per row
#define H_DIM 56
#define W_DIM 56
#define HW 3136
#define N_B 8
#define M_ROWS 25088   // N_B * HW

typedef __bf16 bf16x8 __attribute__((ext_vector_type(8)));
typedef float f32x4 __attribute__((ext_vector_type(4)));

__device__ inline unsigned short f2bf(float f) {
  unsigned u = __float_as_uint(f);
  unsigned r = u + 0x7fffu + ((u >> 16) & 1u);   // RNE
  return (unsigned short)(r >> 16);
}

__device__ inline void gload_lds16(const void* g, void* l) {
  __builtin_amdgcn_global_load_lds(
      (const __attribute__((address_space(1))) void*)g,
      (__attribute__((address_space(3))) void*)l, 16, 0, 0);
}

// ---------------------------------------------------------------------------
// Weight conversion: value_w, out_w -> bf16; om_w -> bf16 zero-padded to 512 rows.
// ---------------------------------------------------------------------------
__global__ __launch_bounds__(256) void convert_w(const float* __restrict__ vw,
                                                 const float* __restrict__ owt,
                                                 const float* __restrict__ omw,
                                                 unsigned short* __restrict__ wv,
                                                 unsigned short* __restrict__ ow,
                                                 unsigned short* __restrict__ wom) {
  int i = blockIdx.x * 256 + threadIdx.x;
  if (i < 65536) {
    wv[i] = f2bf(vw[i]);
  } else if (i < 131072) {
    ow[i - 65536] = f2bf(owt[i - 65536]);
  } else {
    int j = i - 131072;           // 0 .. 512*256-1
    int row = j >> 8;
    wom[j] = (row < OMD) ? f2bf(omw[j]) : (unsigned short)0;
  }
}

// ---------------------------------------------------------------------------
// x (N,C,H,W) fp32 -> xp (N*HW, C) bf16 via 32x32 LDS tile transpose.
// ---------------------------------------------------------------------------
__global__ __launch_bounds__(256) void convert_x(const float* __restrict__ x,
                                                 unsigned short* __restrict__ xp) {
  __shared__ float t[32][33];
  const int tid = threadIdx.x;
  const int pblk = blockIdx.x * 32, cblk = blockIdx.y * 32, n = blockIdx.z;
  const int lp = tid & 31;
  const int c0 = tid >> 5;      // 0..7
#pragma unroll
  for (int i = 0; i < 4; ++i) {
    const int cl = c0 + i * 8;
    t[cl][lp] = x[(size_t)(n * C_DIM + cblk + cl) * HW + pblk + lp];
  }
  __syncthreads();
  const int co = tid & 31;
  const int r0 = tid >> 5;
#pragma unroll
  for (int i = 0; i < 4; ++i) {
    const int rl = r0 + i * 8;
    xp[(size_t)(n * HW + pblk + rl) * C_DIM + cblk + co] = f2bf(t[co][rl]);
  }
}

// ---------------------------------------------------------------------------
// bf16 MFMA GEMM: Y[r,j] = sum_k A[r,k]*B[j,k] + bias[j]
// OUTMODE 0: bf16 row-major stride 256
// OUTMODE 1: fp32 om workspace, padded group layout [r][g][28], col<OMD only
// OUTMODE 2: fp32 NCHW (n*256+col)*HW + p
// ---------------------------------------------------------------------------
template <int OUTMODE>
__global__ __launch_bounds__(256) void gemm_mfma(const unsigned short* __restrict__ A,
                                                 const unsigned short* __restrict__ B,
                                                 const float* __restrict__ bias,
                                                 void* __restrict__ Y) {
  __shared__ unsigned short Asl[128 * 32];
  __shared__ unsigned short Bsl[128 * 32];
  const int tid = threadIdx.x;
  const int wave = tid >> 6;
  const int lane = tid & 63;
  const int rblk = blockIdx.y * 128;
  const int jblk = blockIdx.x * 128;
  const int wm = wave >> 1, wn = wave & 1;
  const int lrow = lane & 15;
  const int lk8 = lane >> 4;

  f32x4 acc[4][4];
#pragma unroll
  for (int i = 0; i < 4; ++i)
#pragma unroll
    for (int j = 0; j < 4; ++j) acc[i][j] = f32x4{0.f, 0.f, 0.f, 0.f};

  const int srow0 = tid >> 2;
  const int skseg = tid & 3;

  for (int k0 = 0; k0 < C_DIM; k0 += 32) {
#pragma unroll
    for (int i = 0; i < 2; ++i) {
      const int row = srow0 + i * 64;
      char* lA = (char*)Asl + (wave * 64 + i * 256) * 16;
      char* lB = (char*)Bsl + (wave * 64 + i * 256) * 16;
      gload_lds16(A + (size_t)(rblk + row) * C_DIM + k0 + skseg * 8, lA);
      gload_lds16(B + (size_t)(jblk + row) * C_DIM + k0 + skseg * 8, lB);
    }
    __syncthreads();
    bf16x8 a[4], b[4];
#pragma unroll
    for (int mi = 0; mi < 4; ++mi)
      a[mi] = *(const bf16x8*)&Asl[(wm * 64 + mi * 16 + lrow) * 32 + lk8 * 8];
#pragma unroll
    for (int nj = 0; nj < 4; ++nj)
      b[nj] = *(const bf16x8*)&Bsl[(wn * 64 + nj * 16 + lrow) * 32 + lk8 * 8];
#pragma unroll
    for (int mi = 0; mi < 4; ++mi)
#pragma unroll
      for (int nj = 0; nj < 4; ++nj)
        acc[mi][nj] = __builtin_amdgcn_mfma_f32_16x16x32_bf16(a[mi], b[nj], acc[mi][nj], 0, 0, 0);
    __syncthreads();
  }

#pragma unroll
  for (int nj = 0; nj < 4; ++nj) {
    const int col = jblk + wn * 64 + nj * 16 + lrow;
    float bs;
    if (OUTMODE == 1) bs = (col < OMD) ? bias[col] : 0.f;
    else bs = bias[col];
    int gidx = 0, eidx = 0;
    if (OUTMODE == 1 && col < OMD) {
      gidx = col / 27;
      eidx = col - gidx * 27;
    }
#pragma unroll
    for (int mi = 0; mi < 4; ++mi) {
#pragma unroll
      for (int rg = 0; rg < 4; ++rg) {
        const int r = rblk + wm * 64 + mi * 16 + lk8 * 4 + rg;
        const float v = acc[mi][nj][rg] + bs;
        if (OUTMODE == 0) {
          ((unsigned short*)Y)[(size_t)r * C_DIM + col] = f2bf(v);
        } else if (OUTMODE == 1) {
          if (col < OMD)
            ((float*)Y)[(size_t)r * OM_RSTRIDE + gidx * OM_GSTRIDE + eidx] = v;
        } else {
          const int n = r / HW;
          const int p = r - n * HW;
          ((float*)Y)[(size_t)(n * C_DIM + col) * HW + p] = v;
        }
      }
    }
  }
}

// ---------------------------------------------------------------------------
// DCNv4 core. Thread = (pixel, group): 16 channels. Block = 16 pixels x 16 groups.
// val: bf16 [M][256]; om: fp32 padded [M][16][28]; core out: bf16 [M][256].
// ---------------------------------------------------------------------------
__device__ inline void acc8(float* acc, uint4 v, float wq) {
#pragma unroll
  for (int j = 0; j < 4; ++j) {
    const unsigned u = ((const unsigned*)&v)[j];
    acc[2 * j]     = fmaf(wq, __uint_as_float(u << 16), acc[2 * j]);
    acc[2 * j + 1] = fmaf(wq, __uint_as_float(u & 0xffff0000u), acc[2 * j + 1]);
  }
}

__global__ __launch_bounds__(256) void dcn_core(const uint4* __restrict__ val4,
                                                const float* __restrict__ om,
                                                uint4* __restrict__ core4) {
  const int tid = threadIdx.x;
  const int g = tid & 15;
  const int pix = tid >> 4;
  const int r = blockIdx.x * 16 + pix;
  const int n = r / HW;
  const int p = r - n * HW;
  const int h = p / W_DIM;
  const int w = p - h * W_DIM;

  // per-thread offsets: 7 x float4 = 28 floats (27 used)
  f32x4 og4[7];
  const float* ogp = om + (size_t)r * OM_RSTRIDE + g * OM_GSTRIDE;
#pragma unroll
  for (int i = 0; i < 7; ++i) og4[i] = *(const f32x4*)(ogp + 4 * i);
  const float* og = (const float*)og4;

  const uint4* vb = val4 + (size_t)n * HW * 32 + g * 2;   // uint4 units, row stride 32

  float acc[16];
#pragma unroll
  for (int i = 0; i < 16; ++i) acc[i] = 0.f;

#pragma unroll
  for (int pp = 0; pp < P_DIM; ++pp) {
    const int ii = pp / 3;
    const int jj = pp - 3 * ii;
    const float offx = og[2 * pp];
    const float offy = og[2 * pp + 1];
    const float m = og[18 + pp];
    const float lh_f = (float)(h - 1 + ii) + offy;
    const float lw_f = (float)(w - 1 + jj) + offx;
    const float h0f = floorf(lh_f);
    const float w0f = floorf(lw_f);
    const float lh = lh_f - h0f;
    const float lw = lw_f - w0f;
    const int h0 = (int)h0f;
    const int w0 = (int)w0f;
    const int h1 = h0 + 1;
    const int w1 = w0 + 1;
    const float hv0 = ((unsigned)h0 < (unsigned)H_DIM) ? 1.f : 0.f;
    const float hv1 = ((unsigned)h1 < (unsigned)H_DIM) ? 1.f : 0.f;
    const float wv0 = ((unsigned)w0 < (unsigned)W_DIM) ? 1.f : 0.f;
    const float wv1 = ((unsigned)w1 < (unsigned)W_DIM) ? 1.f : 0.f;
    const int h0c = min(max(h0, 0), H_DIM - 1);
    const int h1c = min(max(h1, 0), H_DIM - 1);
    const int w0c = min(max(w0, 0), W_DIM - 1);
    const int w1c = min(max(w1, 0), W_DIM - 1);
    const float wq00 = m * (1.f - lh) * (1.f - lw) * hv0 * wv0;
    const float wq01 = m * (1.f - lh) * lw * hv0 * wv1;
    const float wq10 = m * lh * (1.f - lw) * hv1 * wv0;
    const float wq11 = m * lh * lw * hv1 * wv1;
    const int i00 = (h0c * W_DIM + w0c) * 32;
    const int i01 = (h0c * W_DIM + w1c) * 32;
    const int i10 = (h1c * W_DIM + w0c) * 32;
    const int i11 = (h1c * W_DIM + w1c) * 32;
    const uint4 p00a = vb[i00], p00b = vb[i00 + 1];
    const uint4 p01a = vb[i01], p01b = vb[i01 + 1];
    const uint4 p10a = vb[i10], p10b = vb[i10 + 1];
    const uint4 p11a = vb[i11], p11b = vb[i11 + 1];
    acc8(acc, p00a, wq00); acc8(acc + 8, p00b, wq00);
    acc8(acc, p01a, wq01); acc8(acc + 8, p01b, wq01);
    acc8(acc, p10a, wq10); acc8(acc + 8, p10b, wq10);
    acc8(acc, p11a, wq11); acc8(acc + 8, p11b, wq11);
  }

  uint4 o0, o1;
#pragma unroll
  for (int j = 0; j < 4; ++j) {
    ((unsigned*)&o0)[j] = (unsigned)f2bf(acc[2 * j]) | ((unsigned)f2bf(acc[2 * j + 1]) << 16);
    ((unsigned*)&o1)[j] = (unsigned)f2bf(acc[8 + 2 * j]) | ((unsigned)f2bf(acc[8 + 2 * j + 1]) << 16);
  }
  core4[(size_t)r * 32 + g * 2] = o0;
  core4[(size_t)r * 32 + g * 2 + 1] = o1;
}

extern "C" void kernel_launch(void* const* d_in, const int* in_sizes, int n_in,
                              void* d_out, int out_size, void* d_ws, size_t ws_size,
                              hipStream_t stream) {
  const float* x       = (const float*)d_in[0];
  const float* value_w = (const float*)d_in[1];
  const float* value_b = (const float*)d_in[2];
  const float* om_w    = (const float*)d_in[3];
  const float* om_b    = (const float*)d_in[4];
  const float* out_w   = (const float*)d_in[5];
  const float* out_b   = (const float*)d_in[6];
  float* out = (float*)d_out;

  // workspace layout
  char* wsb = (char*)d_ws;
  float* om = (float*)wsb;                                     // 25088*448*4 B
  unsigned short* xp   = (unsigned short*)(wsb + (size_t)M_ROWS * OM_RSTRIDE * 4);
  unsigned short* valb = xp + (size_t)M_ROWS * C_DIM;
  unsigned short* coreb = valb + (size_t)M_ROWS * C_DIM;
  unsigned short* wv  = coreb + (size_t)M_ROWS * C_DIM;
  unsigned short* ow  = wv + C_DIM * C_DIM;
  unsigned short* wom = ow + C_DIM * C_DIM;                    // 512*256

  dim3 blk(256);
  convert_w<<<dim3((2 * C_DIM * C_DIM + OMD_PAD * C_DIM) / 256), blk, 0, stream>>>(
      value_w, out_w, om_w, wv, ow, wom);
  convert_x<<<dim3(98, 8, 8), blk, 0, stream>>>(x, xp);
  // val = xp @ value_w.T + value_b   (bf16 out)
  gemm_mfma<0><<<dim3(2, 196), blk, 0, stream>>>(xp, wv, value_b, valb);
  // om = xp @ om_w.T + om_b          (fp32 padded-group layout)
  gemm_mfma<1><<<dim3(4, 196), blk, 0, stream>>>(xp, wom, om_b, om);
  // deformable sampling
  dcn_core<<<dim3(M_ROWS / 16), blk, 0, stream>>>((const uint4*)valb, om, (uint4*)coreb);
  // out = core @ out_w.T + out_b     (fp32 NCHW)
  gemm_mfma<2><<<dim3(2, 196), blk, 0, stream>>>(coreb, ow, out_b, out);
}